// Round 1
// baseline (474.305 us; speedup 1.0000x reference)
//
#include <hip/hip_runtime.h>
#include <hip/hip_bf16.h>
#include <stdint.h>

typedef float f32x2 __attribute__((ext_vector_type(2)));
typedef float f32x4 __attribute__((ext_vector_type(4)));
typedef short short8 __attribute__((ext_vector_type(8)));

#define B_ 4096
#define T_ 256
#define D_ 18
#define H_ 32
#define GK 8192   // T_*H_
#define GN 512

// ---------- helpers ----------
__device__ __forceinline__ unsigned short f2bf(float x) {
  unsigned u = __builtin_bit_cast(unsigned, x);
  u += 0x7FFFu + ((u >> 16) & 1u);   // round-to-nearest-even
  return (unsigned short)(u >> 16);
}
__device__ __forceinline__ float fsig(float x) {
  float e = __builtin_amdgcn_exp2f(-1.442695041f * x);
  return __builtin_amdgcn_rcpf(1.0f + e);
}
__device__ __forceinline__ float ftanh(float x) {
  float e = __builtin_amdgcn_exp2f(-2.885390082f * x);
  return 2.0f * __builtin_amdgcn_rcpf(1.0f + e) - 1.0f;
}

// ---------- kernel 1: W1 fp32 -> bf16 ----------
__global__ __launch_bounds__(256) void cvtw1_kernel(const float* __restrict__ w1,
                                                    unsigned short* __restrict__ dst) {
  int i = blockIdx.x * 256 + threadIdx.x;         // float4 index, total 1048576
  float4 v = ((const float4*)w1)[i];
  unsigned lo = (unsigned)f2bf(v.x) | ((unsigned)f2bf(v.y) << 16);
  unsigned hi = (unsigned)f2bf(v.z) | ((unsigned)f2bf(v.w) << 16);
  uint2 o; o.x = lo; o.y = hi;
  ((uint2*)dst)[i] = o;
}

// ---------- kernel 2: fused LSTM (1 wave = 1 batch element) ----------
// lane L owns gate rows L (i for L<32, f for L>=32) and L+64 (g / o)
__global__ __launch_bounds__(256, 4) void lstm_kernel(
    const float* __restrict__ batch, const float* __restrict__ W_ih,
    const float* __restrict__ W_hh, const float* __restrict__ b_ih,
    const float* __restrict__ b_hh, unsigned short* __restrict__ hs) {
  const int lane = (int)(threadIdx.x & 63);
  int b = (int)(blockIdx.x * 4 + (threadIdx.x >> 6));
  b = __builtin_amdgcn_readfirstlane(b);

  const int r0 = lane;
  const int r1 = lane + 64;

  f32x2 wih[D_], whh[H_];
#pragma unroll
  for (int d = 0; d < D_; ++d) { wih[d][0] = W_ih[r0 * D_ + d]; wih[d][1] = W_ih[r1 * D_ + d]; }
#pragma unroll
  for (int k = 0; k < H_; ++k) { whh[k][0] = W_hh[r0 * H_ + k]; whh[k][1] = W_hh[r1 * H_ + k]; }
  f32x2 bias; bias[0] = b_ih[r0] + b_hh[r0]; bias[1] = b_ih[r1] + b_hh[r1];

  float hsg[H_];
#pragma unroll
  for (int k = 0; k < H_; ++k) hsg[k] = 0.0f;
  float c = 0.0f;

  const float* xrow = batch + (size_t)b * (T_ * D_);
  unsigned short* hrow = hs + (size_t)b * (T_ * H_);
  const bool lo = (lane < 32);

  for (int t = 0; t < T_; ++t) {
    // two accumulator chains (hide fma latency), h-part first (shields x s_loads)
    f32x2 a0 = bias;
    f32x2 a1; a1[0] = 0.0f; a1[1] = 0.0f;
#pragma unroll
    for (int k = 0; k < 16; ++k) {
      f32x2 hv0; hv0[0] = hsg[k]; hv0[1] = hsg[k];
      a0 = __builtin_elementwise_fma(whh[k], hv0, a0);
      f32x2 hv1; hv1[0] = hsg[k + 16]; hv1[1] = hsg[k + 16];
      a1 = __builtin_elementwise_fma(whh[k + 16], hv1, a1);
    }
#pragma unroll
    for (int d = 0; d < 9; ++d) {
      float x0 = xrow[d], x1 = xrow[d + 9];
      f32x2 xv0; xv0[0] = x0; xv0[1] = x0;
      a0 = __builtin_elementwise_fma(wih[d], xv0, a0);
      f32x2 xv1; xv1[0] = x1; xv1[1] = x1;
      a1 = __builtin_elementwise_fma(wih[d + 9], xv1, a1);
    }
    xrow += D_;
    f32x2 g2 = a0 + a1;

    // component 0: sigmoid (i or f); component 1: tanh (g) if lo else sigmoid (o)
    float sx = fsig(g2[0]);
    float zy = lo ? (2.0f * g2[1]) : g2[1];
    float sgy = fsig(zy);
    float sy = lo ? (2.0f * sgy - 1.0f) : sgy;

    float ox = __shfl_xor(sx, 32);
    float oy = __shfl_xor(sy, 32);
    float iv = lo ? sx : ox;
    float fv = lo ? ox : sx;
    float gv = lo ? sy : oy;
    float ov = lo ? oy : sy;

    c = fmaf(fv, c, iv * gv);
    float h = ov * ftanh(c);
    if (lo) hrow[t * H_ + lane] = f2bf(h);

#pragma unroll
    for (int k = 0; k < H_; ++k)
      hsg[k] = __builtin_bit_cast(float, __builtin_amdgcn_readlane(__builtin_bit_cast(int, h), k));
  }
}

// ---------- kernel 3: bf16 MFMA GEMM, BM=BN=128, BK=64, split-K=4 ----------
// A = hs [4096 x 8192], B = W1bf [512 x 8192] (both K-contiguous), atomicAdd partials
__global__ __launch_bounds__(256, 2) void gemm_kernel(
    const unsigned short* __restrict__ Ahs, const unsigned short* __restrict__ Bw1,
    float* __restrict__ hid) {
  __shared__ short As[128 * 64];
  __shared__ short Bs[128 * 64];

  const int bid = (int)blockIdx.x;
  const int mt_ = bid & 31;          // 32 m-tiles
  const int nt_ = (bid >> 5) & 3;    // 4 n-tiles
  const int kt_ = bid >> 7;          // 4 k-splits
  const int m0 = mt_ << 7;
  const int n0 = nt_ << 7;
  const int k0 = kt_ << 11;          // * 2048

  const int tid = (int)threadIdx.x;
  const int lane = tid & 63, w = tid >> 6;
  const int wm = w & 1, wn = w >> 1;
  const int lq = lane >> 4, lr = lane & 15;

  // staging: chunk position p holds global chunk cg = (p&7) ^ ((p>>3)&7) of row p>>3
  const short* gA[4];
  const short* gB[4];
  int lp[4];
#pragma unroll
  for (int j = 0; j < 4; ++j) {
    int p = tid + 256 * j;
    int row = p >> 3, q = p & 7, cg = q ^ (row & 7);
    gA[j] = (const short*)Ahs + (size_t)(m0 + row) * GK + k0 + cg * 8;
    gB[j] = (const short*)Bw1 + (size_t)(n0 + row) * GK + k0 + cg * 8;
    lp[j] = p * 8;
  }

  // fragment LDS offsets (loop-invariant)
  int offA[4][2], offB[4][2];
#pragma unroll
  for (int mt = 0; mt < 4; ++mt) {
#pragma unroll
    for (int ks = 0; ks < 2; ++ks) {
      int m = wm * 64 + mt * 16 + lr;
      offA[mt][ks] = m * 64 + (((lq + ks * 4) ^ (m & 7)) * 8);
      int n = wn * 64 + mt * 16 + lr;
      offB[mt][ks] = n * 64 + (((lq + ks * 4) ^ (n & 7)) * 8);
    }
  }

  f32x4 acc[4][4];
#pragma unroll
  for (int mt = 0; mt < 4; ++mt)
#pragma unroll
    for (int nt = 0; nt < 4; ++nt) { acc[mt][nt][0] = 0.f; acc[mt][nt][1] = 0.f; acc[mt][nt][2] = 0.f; acc[mt][nt][3] = 0.f; }

  for (int it = 0; it < 32; ++it) {
    short8 va[4], vb[4];
#pragma unroll
    for (int j = 0; j < 4; ++j) {
      va[j] = *(const short8*)(gA[j]); gA[j] += 64;
      vb[j] = *(const short8*)(gB[j]); gB[j] += 64;
    }
    __syncthreads();
#pragma unroll
    for (int j = 0; j < 4; ++j) {
      *(short8*)(&As[lp[j]]) = va[j];
      *(short8*)(&Bs[lp[j]]) = vb[j];
    }
    __syncthreads();

    short8 af[4][2], bf[4][2];
#pragma unroll
    for (int mt = 0; mt < 4; ++mt) {
#pragma unroll
      for (int ks = 0; ks < 2; ++ks) {
        af[mt][ks] = *(const short8*)(&As[offA[mt][ks]]);
        bf[mt][ks] = *(const short8*)(&Bs[offB[mt][ks]]);
      }
    }
#pragma unroll
    for (int ks = 0; ks < 2; ++ks)
#pragma unroll
      for (int mt = 0; mt < 4; ++mt)
#pragma unroll
        for (int nt = 0; nt < 4; ++nt)
          acc[mt][nt] = __builtin_amdgcn_mfma_f32_16x16x32_bf16(af[mt][ks], bf[nt][ks], acc[mt][nt], 0, 0, 0);
  }

  // epilogue: C layout col=lane&15, row=(lane>>4)*4+reg
#pragma unroll
  for (int mt = 0; mt < 4; ++mt) {
#pragma unroll
    for (int nt = 0; nt < 4; ++nt) {
      int n = n0 + wn * 64 + nt * 16 + lr;
#pragma unroll
      for (int r = 0; r < 4; ++r) {
        int m = m0 + wm * 64 + mt * 16 + lq * 4 + r;
        atomicAdd(&hid[(size_t)m * GN + n], acc[mt][nt][r]);
      }
    }
  }
}

// ---------- kernel 4: head — out[b] = sum_n W2[n]*relu(hid[b,n]+b1[n]) + b2 ----------
__global__ __launch_bounds__(256) void head_kernel(const float* __restrict__ hid,
                                                   const float* __restrict__ b1,
                                                   const float* __restrict__ W2,
                                                   const float* __restrict__ b2,
                                                   float* __restrict__ out) {
  const int b = (int)(blockIdx.x * 4 + (threadIdx.x >> 6));
  const int l = (int)(threadIdx.x & 63);
  const float4* h4 = (const float4*)(hid + (size_t)b * GN);
  const float4* b14 = (const float4*)b1;
  const float4* w4 = (const float4*)W2;
  float s = 0.0f;
#pragma unroll
  for (int p = 0; p < 2; ++p) {
    int i = p * 64 + l;
    float4 hv = h4[i], bv = b14[i], wv = w4[i];
    float t0 = fmaxf(hv.x + bv.x, 0.0f);
    float t1 = fmaxf(hv.y + bv.y, 0.0f);
    float t2 = fmaxf(hv.z + bv.z, 0.0f);
    float t3 = fmaxf(hv.w + bv.w, 0.0f);
    s = fmaf(t0, wv.x, s); s = fmaf(t1, wv.y, s);
    s = fmaf(t2, wv.z, s); s = fmaf(t3, wv.w, s);
  }
#pragma unroll
  for (int off = 32; off >= 1; off >>= 1) s += __shfl_xor(s, off);
  if (l == 0) out[b] = s + b2[0];
}

extern "C" void kernel_launch(void* const* d_in, const int* in_sizes, int n_in,
                              void* d_out, int out_size, void* d_ws, size_t ws_size,
                              hipStream_t stream) {
  const float* batch = (const float*)d_in[0];
  const float* W_ih = (const float*)d_in[1];
  const float* W_hh = (const float*)d_in[2];
  const float* b_ih = (const float*)d_in[3];
  const float* b_hh = (const float*)d_in[4];
  const float* W1 = (const float*)d_in[5];
  const float* b1 = (const float*)d_in[6];
  const float* W2 = (const float*)d_in[7];
  const float* b2 = (const float*)d_in[8];
  float* out = (float*)d_out;

  char* ws = (char*)d_ws;
  unsigned short* hs = (unsigned short*)ws;                          // 4096*8192*2  = 67108864 B
  unsigned short* w1b = (unsigned short*)(ws + 67108864);            // 512*8192*2   =  8388608 B
  float* hid = (float*)(ws + 67108864 + 8388608);                    // 4096*512*4   =  8388608 B

  hipMemsetAsync(hid, 0, (size_t)B_ * GN * sizeof(float), stream);
  cvtw1_kernel<<<4096, 256, 0, stream>>>(W1, w1b);
  lstm_kernel<<<1024, 256, 0, stream>>>(batch, W_ih, W_hh, b_ih, b_hh, hs);
  gemm_kernel<<<512, 256, 0, stream>>>(hs, w1b, hid);
  head_kernel<<<1024, 256, 0, stream>>>(hid, b1, W2, b2, out);
}

// Round 2
// 358.897 us; speedup vs baseline: 1.3216x; 1.3216x over previous
//
#include <hip/hip_runtime.h>
#include <hip/hip_bf16.h>
#include <stdint.h>

typedef float f32x2 __attribute__((ext_vector_type(2)));
typedef float f32x4 __attribute__((ext_vector_type(4)));
typedef short short8 __attribute__((ext_vector_type(8)));

#define B_ 4096
#define T_ 256
#define D_ 18
#define H_ 32
#define GK 8192   // T_*H_
#define GN 512

// ---------- helpers ----------
__device__ __forceinline__ unsigned short f2bf(float x) {
  unsigned u = __builtin_bit_cast(unsigned, x);
  u += 0x7FFFu + ((u >> 16) & 1u);   // round-to-nearest-even
  return (unsigned short)(u >> 16);
}
__device__ __forceinline__ float fsig(float x) {
  float e = __builtin_amdgcn_exp2f(-1.442695041f * x);
  return __builtin_amdgcn_rcpf(1.0f + e);
}
__device__ __forceinline__ float ftanh(float x) {
  float e = __builtin_amdgcn_exp2f(-2.885390082f * x);
  return 2.0f * __builtin_amdgcn_rcpf(1.0f + e) - 1.0f;
}

// ---------- kernel 1: W1 fp32 -> bf16 ----------
__global__ __launch_bounds__(256) void cvtw1_kernel(const float* __restrict__ w1,
                                                    unsigned short* __restrict__ dst) {
  int i = blockIdx.x * 256 + threadIdx.x;         // float4 index, total 1048576
  float4 v = ((const float4*)w1)[i];
  unsigned lo = (unsigned)f2bf(v.x) | ((unsigned)f2bf(v.y) << 16);
  unsigned hi = (unsigned)f2bf(v.z) | ((unsigned)f2bf(v.w) << 16);
  uint2 o; o.x = lo; o.y = hi;
  ((uint2*)dst)[i] = o;
}

// ---------- kernel 2: MFMA LSTM ----------
// Block = 512 threads (8 waves) handles 16 batch elements.
// Wave w owns M-tile w: 16 permuted gate rows; tile-row m = h_local*4 + gate,
// h_row = w*4 + h_local, gate order (i,f,g,o). Original W row = gate*32 + h_row.
// Per timestep: acc[16x16] = bias + W_x @ x_t + W_h @ (h_hi + h_lo)   (3 MFMAs)
// C layout: col(elem) = lane&15, row = (lane>>4)*4 + reg  ->  reg r = gate r of
// h_row = w*4 + (lane>>4) for element lane&15. c lives in ONE register per lane.
// h exchanged via LDS (bf16 hi/lo, B-frag layout [n][k]); x staged 1 step ahead.
__global__ __launch_bounds__(512) void lstm_kernel(
    const float* __restrict__ batch, const float* __restrict__ W_ih,
    const float* __restrict__ W_hh, const float* __restrict__ b_ih,
    const float* __restrict__ b_hh, unsigned short* __restrict__ hs) {
  __shared__ unsigned short xb[2 * 16 * 32];    // [buf][n][k] k<18 = x, else 0
  __shared__ unsigned short hbhi[2 * 16 * 32];  // [buf][n][k=h_row]
  __shared__ unsigned short hblo[2 * 16 * 32];

  const int tid = (int)threadIdx.x;
  const int lane = tid & 63;
  const int w = tid >> 6;          // M-tile / h-row group
  const int lq = lane >> 4;        // quad
  const int lr = lane & 15;        // row-in-tile (A) / element n (B,C)
  const int b0 = (int)blockIdx.x * 16;

  // ---- load constant fragments (once) ----
  short8 wx, wh;
  {
    int m = lr;                                    // tile-row for A-frag
    int grow = (m & 3) * 32 + w * 4 + (m >> 2);    // original gate row
#pragma unroll
    for (int j = 0; j < 8; ++j) {
      int k = lq * 8 + j;
      wx[j] = (k < D_) ? (short)f2bf(W_ih[grow * D_ + k]) : (short)0;
      wh[j] = (short)f2bf(W_hh[grow * H_ + k]);
    }
  }
  f32x4 bias4;
#pragma unroll
  for (int r = 0; r < 4; ++r) {
    int g = r * 32 + w * 4 + lq;
    bias4[r] = b_ih[g] + b_hh[g];
  }

  // ---- init LDS: zero everything (covers x pad + h(0)=0) ----
  for (int i = tid; i < 1024; i += 512) {
    xb[i] = 0; hbhi[i] = 0; hblo[i] = 0;
  }
  __syncthreads();
  // stage x(0) into xb buf 0
  if (tid < 288) {
    int n = tid / 18, d = tid - n * 18;
    xb[n * 32 + d] = f2bf(batch[((size_t)(b0 + n) * T_ + 0) * D_ + d]);
  }
  __syncthreads();

  float c = 0.0f;

  for (int t = 0; t < T_; ++t) {
    const int p = t & 1;

    // stage x(t+1) into the other buffer (read next iter, after barrier)
    if (t < T_ - 1 && tid < 288) {
      int n = tid / 18, d = tid - n * 18;
      float xv = batch[((size_t)(b0 + n) * T_ + (t + 1)) * D_ + d];
      xb[(p ^ 1) * 512 + n * 32 + d] = f2bf(xv);
    }

    // B-fragments: lane holds [k = lq*8+j][n = lr]
    short8 xf = *(const short8*)&xb[p * 512 + lr * 32 + lq * 8];
    short8 hf_hi = *(const short8*)&hbhi[p * 512 + lr * 32 + lq * 8];
    short8 hf_lo = *(const short8*)&hblo[p * 512 + lr * 32 + lq * 8];

    f32x4 acc = bias4;
    acc = __builtin_amdgcn_mfma_f32_16x16x32_bf16(wx, xf, acc, 0, 0, 0);
    acc = __builtin_amdgcn_mfma_f32_16x16x32_bf16(wh, hf_hi, acc, 0, 0, 0);
    acc = __builtin_amdgcn_mfma_f32_16x16x32_bf16(wh, hf_lo, acc, 0, 0, 0);

    float iv = fsig(acc[0]);
    float fv = fsig(acc[1]);
    float gv = ftanh(acc[2]);
    float ov = fsig(acc[3]);
    c = fmaf(fv, c, iv * gv);
    float h = ov * ftanh(c);

    unsigned short h_hi = f2bf(h);
    hs[((size_t)(b0 + lr) * T_ + t) * H_ + (w * 4 + lq)] = h_hi;
    float hfv = __builtin_bit_cast(float, (unsigned)h_hi << 16);
    unsigned short h_lo = f2bf(h - hfv);

    hbhi[(p ^ 1) * 512 + lr * 32 + (w * 4 + lq)] = h_hi;
    hblo[(p ^ 1) * 512 + lr * 32 + (w * 4 + lq)] = h_lo;

    __syncthreads();
  }
}

// ---------- kernel 3: bf16 MFMA GEMM, BM=BN=128, BK=64, split-K=4 ----------
// A = hs [4096 x 8192], B = W1bf [512 x 8192] (both K-contiguous), atomicAdd partials
__global__ __launch_bounds__(256, 2) void gemm_kernel(
    const unsigned short* __restrict__ Ahs, const unsigned short* __restrict__ Bw1,
    float* __restrict__ hid) {
  __shared__ short As[128 * 64];
  __shared__ short Bs[128 * 64];

  const int bid = (int)blockIdx.x;
  const int mt_ = bid & 31;          // 32 m-tiles
  const int nt_ = (bid >> 5) & 3;    // 4 n-tiles
  const int kt_ = bid >> 7;          // 4 k-splits
  const int m0 = mt_ << 7;
  const int n0 = nt_ << 7;
  const int k0 = kt_ << 11;          // * 2048

  const int tid = (int)threadIdx.x;
  const int lane = tid & 63, w = tid >> 6;
  const int wm = w & 1, wn = w >> 1;
  const int lq = lane >> 4, lr = lane & 15;

  // staging: chunk position p holds global chunk cg = (p&7) ^ ((p>>3)&7) of row p>>3
  const short* gA[4];
  const short* gB[4];
  int lp[4];
#pragma unroll
  for (int j = 0; j < 4; ++j) {
    int p = tid + 256 * j;
    int row = p >> 3, q = p & 7, cg = q ^ (row & 7);
    gA[j] = (const short*)Ahs + (size_t)(m0 + row) * GK + k0 + cg * 8;
    gB[j] = (const short*)Bw1 + (size_t)(n0 + row) * GK + k0 + cg * 8;
    lp[j] = p * 8;
  }

  // fragment LDS offsets (loop-invariant)
  int offA[4][2], offB[4][2];
#pragma unroll
  for (int mt = 0; mt < 4; ++mt) {
#pragma unroll
    for (int ks = 0; ks < 2; ++ks) {
      int m = wm * 64 + mt * 16 + lr;
      offA[mt][ks] = m * 64 + (((lq + ks * 4) ^ (m & 7)) * 8);
      int n = wn * 64 + mt * 16 + lr;
      offB[mt][ks] = n * 64 + (((lq + ks * 4) ^ (n & 7)) * 8);
    }
  }

  f32x4 acc[4][4];
#pragma unroll
  for (int mt = 0; mt < 4; ++mt)
#pragma unroll
    for (int nt = 0; nt < 4; ++nt) { acc[mt][nt][0] = 0.f; acc[mt][nt][1] = 0.f; acc[mt][nt][2] = 0.f; acc[mt][nt][3] = 0.f; }

  for (int it = 0; it < 32; ++it) {
    short8 va[4], vb[4];
#pragma unroll
    for (int j = 0; j < 4; ++j) {
      va[j] = *(const short8*)(gA[j]); gA[j] += 64;
      vb[j] = *(const short8*)(gB[j]); gB[j] += 64;
    }
    __syncthreads();
#pragma unroll
    for (int j = 0; j < 4; ++j) {
      *(short8*)(&As[lp[j]]) = va[j];
      *(short8*)(&Bs[lp[j]]) = vb[j];
    }
    __syncthreads();

    short8 af[4][2], bf[4][2];
#pragma unroll
    for (int mt = 0; mt < 4; ++mt) {
#pragma unroll
      for (int ks = 0; ks < 2; ++ks) {
        af[mt][ks] = *(const short8*)(&As[offA[mt][ks]]);
        bf[mt][ks] = *(const short8*)(&Bs[offB[mt][ks]]);
      }
    }
#pragma unroll
    for (int ks = 0; ks < 2; ++ks)
#pragma unroll
      for (int mt = 0; mt < 4; ++mt)
#pragma unroll
        for (int nt = 0; nt < 4; ++nt)
          acc[mt][nt] = __builtin_amdgcn_mfma_f32_16x16x32_bf16(af[mt][ks], bf[nt][ks], acc[mt][nt], 0, 0, 0);
  }

  // epilogue: C layout col=lane&15, row=(lane>>4)*4+reg
#pragma unroll
  for (int mt = 0; mt < 4; ++mt) {
#pragma unroll
    for (int nt = 0; nt < 4; ++nt) {
      int n = n0 + wn * 64 + nt * 16 + lr;
#pragma unroll
      for (int r = 0; r < 4; ++r) {
        int m = m0 + wm * 64 + mt * 16 + lq * 4 + r;
        atomicAdd(&hid[(size_t)m * GN + n], acc[mt][nt][r]);
      }
    }
  }
}

// ---------- kernel 4: head — out[b] = sum_n W2[n]*relu(hid[b,n]+b1[n]) + b2 ----------
__global__ __launch_bounds__(256) void head_kernel(const float* __restrict__ hid,
                                                   const float* __restrict__ b1,
                                                   const float* __restrict__ W2,
                                                   const float* __restrict__ b2,
                                                   float* __restrict__ out) {
  const int b = (int)(blockIdx.x * 4 + (threadIdx.x >> 6));
  const int l = (int)(threadIdx.x & 63);
  const float4* h4 = (const float4*)(hid + (size_t)b * GN);
  const float4* b14 = (const float4*)b1;
  const float4* w4 = (const float4*)W2;
  float s = 0.0f;
#pragma unroll
  for (int p = 0; p < 2; ++p) {
    int i = p * 64 + l;
    float4 hv = h4[i], bv = b14[i], wv = w4[i];
    float t0 = fmaxf(hv.x + bv.x, 0.0f);
    float t1 = fmaxf(hv.y + bv.y, 0.0f);
    float t2 = fmaxf(hv.z + bv.z, 0.0f);
    float t3 = fmaxf(hv.w + bv.w, 0.0f);
    s = fmaf(t0, wv.x, s); s = fmaf(t1, wv.y, s);
    s = fmaf(t2, wv.z, s); s = fmaf(t3, wv.w, s);
  }
#pragma unroll
  for (int off = 32; off >= 1; off >>= 1) s += __shfl_xor(s, off);
  if (l == 0) out[b] = s + b2[0];
}

extern "C" void kernel_launch(void* const* d_in, const int* in_sizes, int n_in,
                              void* d_out, int out_size, void* d_ws, size_t ws_size,
                              hipStream_t stream) {
  const float* batch = (const float*)d_in[0];
  const float* W_ih = (const float*)d_in[1];
  const float* W_hh = (const float*)d_in[2];
  const float* b_ih = (const float*)d_in[3];
  const float* b_hh = (const float*)d_in[4];
  const float* W1 = (const float*)d_in[5];
  const float* b1 = (const float*)d_in[6];
  const float* W2 = (const float*)d_in[7];
  const float* b2 = (const float*)d_in[8];
  float* out = (float*)d_out;

  char* ws = (char*)d_ws;
  unsigned short* hs = (unsigned short*)ws;                          // 4096*8192*2  = 67108864 B
  unsigned short* w1b = (unsigned short*)(ws + 67108864);            // 512*8192*2   =  8388608 B
  float* hid = (float*)(ws + 67108864 + 8388608);                    // 4096*512*4   =  8388608 B

  hipMemsetAsync(hid, 0, (size_t)B_ * GN * sizeof(float), stream);
  cvtw1_kernel<<<4096, 256, 0, stream>>>(W1, w1b);
  lstm_kernel<<<256, 512, 0, stream>>>(batch, W_ih, W_hh, b_ih, b_hh, hs);
  gemm_kernel<<<512, 256, 0, stream>>>(hs, w1b, hid);
  head_kernel<<<1024, 256, 0, stream>>>(hid, b1, W2, b2, out);
}